// Round 4
// baseline (68.251 us; speedup 1.0000x reference)
//
#include <hip/hip_runtime.h>

#define PNUM    1024
#define NB      128
#define NBLOCKS (NB * 16)

typedef _Float16 h2 __attribute__((ext_vector_type(2)));

// padded LDS word index: +1 word every 8 -> gt banks (9s+4j)%32 = 2 lanes/bank (free)
#define PW(e) ((e) + ((e) >> 3))

// smooth-L1 identity: sl1(d) = m*(|d| - 0.5m), m = min(|d|,1)   (5 packed ops)
#define SL1(acc, p, g) do {                               \
    h2 d_ = (p) - (g);                                    \
    h2 a_ = __builtin_elementwise_abs(d_);                \
    h2 m_ = __builtin_elementwise_min(a_, one2);          \
    h2 t_ = __builtin_elementwise_fma(m_, nh2, a_);       \
    (acc) = __builtin_elementwise_fma(m_, t_, (acc)); } while (0)

// One block = (batch b, 64 consecutive shifts). 256 threads =
// 8 shift-slots (8 shifts each, rolling 11-wide gt window) x 32 j-slots (32 j each).
__global__ __launch_bounds__(256, 8) void poly_kernel(
    const float* __restrict__ pred, const float* __restrict__ gt,
    float* __restrict__ block_min, unsigned* __restrict__ counter,
    float* __restrict__ out) {
  __shared__ h2    pred_s[1151];     // PW(1023)=1150
  __shared__ h2    gt_s[1223];       // PW(1087)=1222
  __shared__ float partial[4][64];   // per-wave partial sums
  __shared__ int   lastflag;

  const int b     = blockIdx.x >> 4;
  const int chunk = blockIdx.x & 15;
  const int t     = threadIdx.x;

  const float4* pred4 = (const float4*)(pred + (size_t)b * (PNUM * 2));
  const float4* gt4   = (const float4*)(gt   + (size_t)b * (PNUM * 2));
  const int gb2 = chunk * 32;        // gt float4 base (gb = chunk*64 elements)

  // ---- stage pred (512 h2-pairs) and gt (544 h2-pairs, wrapped) into padded LDS
  #pragma unroll
  for (int r = 0; r < 2; ++r) {
    int p = t + r * 256;
    float4 v = pred4[p];
    int w = PW(2 * p);               // 2p even -> pair never crosses pad boundary
    pred_s[w]     = h2{(_Float16)v.x, (_Float16)v.y};
    pred_s[w + 1] = h2{(_Float16)v.z, (_Float16)v.w};
  }
  #pragma unroll
  for (int r = 0; r < 2; ++r) {
    int u = t + r * 256;
    float4 v = gt4[(gb2 + u) & 511];
    int w = PW(2 * u);
    gt_s[w]     = h2{(_Float16)v.x, (_Float16)v.y};
    gt_s[w + 1] = h2{(_Float16)v.z, (_Float16)v.w};
  }
  if (t < 32) {                      // pairs 512..543 -> elements 1024..1087
    int u = t + 512;
    float4 v = gt4[(gb2 + u) & 511];
    int w = PW(2 * u);
    gt_s[w]     = h2{(_Float16)v.x, (_Float16)v.y};
    gt_s[w + 1] = h2{(_Float16)v.z, (_Float16)v.w};
  }
  __syncthreads();

  const int sslot = t & 7;           // shifts i0 = chunk*64 + sslot*8 + s, s=0..7
  const int jslot = t >> 3;          // j = jslot*32 + jj, jj=0..31
  const h2* Pp = pred_s + 36 * jslot;            // PW(32*jslot)
  const h2* Gp = gt_s   + 9 * sslot + 36 * jslot; // PW(8*sslot+32*jslot)

  const h2 one2 = {(_Float16)1.0f,  (_Float16)1.0f};
  const h2 nh2  = {(_Float16)-0.5f, (_Float16)-0.5f};
  h2 acc[8];
  #pragma unroll
  for (int s = 0; s < 8; ++s) acc[s] = h2{(_Float16)0.0f, (_Float16)0.0f};

  // rolling window w[i] = gt element kbase + 4g + i
  h2 w[11];
  #pragma unroll
  for (int e = 0; e < 7; ++e) w[e] = Gp[PW(e)];

  #pragma unroll
  for (int g = 0; g < 8; ++g) {      // 8 groups x 4 jj = 32 j per thread
    const int e0 = 4 * g;
    h2 p0 = Pp[PW(e0)], p1 = Pp[PW(e0 + 1)], p2 = Pp[PW(e0 + 2)], p3 = Pp[PW(e0 + 3)];
    w[7]  = Gp[PW(e0 + 7)];
    w[8]  = Gp[PW(e0 + 8)];
    w[9]  = Gp[PW(e0 + 9)];
    w[10] = Gp[PW(e0 + 10)];
    #pragma unroll
    for (int s = 0; s < 8; ++s) SL1(acc[s], p0, w[s]);
    #pragma unroll
    for (int s = 0; s < 8; ++s) SL1(acc[s], p1, w[s + 1]);
    #pragma unroll
    for (int s = 0; s < 8; ++s) SL1(acc[s], p2, w[s + 2]);
    #pragma unroll
    for (int s = 0; s < 8; ++s) SL1(acc[s], p3, w[s + 3]);
    #pragma unroll
    for (int i = 0; i < 7; ++i) w[i] = w[i + 4];
  }

  // ---- reduce over jslot (bits 3..5 of lane) via shuffles
  float f[8];
  #pragma unroll
  for (int s = 0; s < 8; ++s) f[s] = (float)acc[s].x + (float)acc[s].y;
  #pragma unroll
  for (int s = 0; s < 8; ++s) {
    f[s] += __shfl_xor(f[s], 8);
    f[s] += __shfl_xor(f[s], 16);
    f[s] += __shfl_xor(f[s], 32);
  }
  const int wid = t >> 6, lane = t & 63;
  if ((lane & 56) == 0) {            // lanes 0..7: sslot = lane
    #pragma unroll
    for (int s = 0; s < 8; ++s) partial[wid][lane * 8 + s] = f[s];
  }
  __syncthreads();

  // ---- per-block: sum 4 wave-partials per shift, min over 64 shifts
  if (t < 64) {
    float sum = partial[0][t] + partial[1][t] + partial[2][t] + partial[3][t];
    float dis = sum * (1.0f / 1024.0f);
    #pragma unroll
    for (int off = 32; off; off >>= 1)
      dis = fminf(dis, __shfl_xor(dis, off));
    if (t == 0) {
      __hip_atomic_store(&block_min[blockIdx.x], dis,
                         __ATOMIC_RELEASE, __HIP_MEMORY_SCOPE_AGENT);
      unsigned old = __hip_atomic_fetch_add(counter, 1u,
                         __ATOMIC_ACQ_REL, __HIP_MEMORY_SCOPE_AGENT);
      lastflag = (old == NBLOCKS - 1);
    }
  }
  __syncthreads();

  // ---- last block: per-batch min over 16 chunks, mean over 128 batches
  if (lastflag) {
    float m = 0.0f;
    if (t < NB) {
      m = __hip_atomic_load(&block_min[t * 16],
                            __ATOMIC_ACQUIRE, __HIP_MEMORY_SCOPE_AGENT);
      #pragma unroll
      for (int c = 1; c < 16; ++c) {
        float v = __hip_atomic_load(&block_min[t * 16 + c],
                                    __ATOMIC_ACQUIRE, __HIP_MEMORY_SCOPE_AGENT);
        m = fminf(m, v);
      }
    }
    #pragma unroll
    for (int off = 32; off; off >>= 1) m += __shfl_xor(m, off);
    if (t < NB && (t & 63) == 0) partial[0][t >> 6] = m;
    __syncthreads();
    if (t == 0) out[0] = (partial[0][0] + partial[0][1]) * (1.0f / NB);
  }
}

extern "C" void kernel_launch(void* const* d_in, const int* in_sizes, int n_in,
                              void* d_out, int out_size, void* d_ws, size_t ws_size,
                              hipStream_t stream) {
  const float* pred = (const float*)d_in[0];
  const float* gt   = (const float*)d_in[1];
  float* out        = (float*)d_out;
  float* block_min  = (float*)d_ws;                          // 2048 floats
  unsigned* counter = (unsigned*)((char*)d_ws + NBLOCKS * 4);

  hipMemsetAsync(counter, 0, 4, stream);
  poly_kernel<<<NBLOCKS, 256, 0, stream>>>(pred, gt, block_min, counter, out);
}